// Round 2
// baseline (1014.935 us; speedup 1.0000x reference)
//
#include <hip/hip_runtime.h>
#include <hip/hip_bf16.h>
#include <stdint.h>
#include <stddef.h>

#define T_SEQ 2048
#define DIM   4096
#define NH    32
#define NKV   8
#define HD    128

using bf16 = __hip_bfloat16;
typedef __attribute__((ext_vector_type(8))) short bf16x8;
typedef __attribute__((ext_vector_type(4))) float f32x4;

__device__ __forceinline__ void gload_lds16(const void* g, void* l) {
  __builtin_amdgcn_global_load_lds(
      (const __attribute__((address_space(1))) unsigned int*)g,
      (__attribute__((address_space(3))) unsigned int*)l, 16, 0, 0);
}

__device__ __forceinline__ unsigned short f2bf(float x) {
  bf16 h = __float2bfloat16(x);
  return *reinterpret_cast<unsigned short*>(&h);
}

// ---------------- fp32 -> bf16 convert (vectorized, grid-stride) ----------------
__global__ __launch_bounds__(256) void cvt_kernel(const float* __restrict__ in,
                                                  unsigned short* __restrict__ out, int n) {
  const int idx = blockIdx.x * blockDim.x + threadIdx.x;
  const int stride = gridDim.x * blockDim.x;
  for (int i = idx * 4; i < n; i += stride * 4) {
    float4 v = *(const float4*)(in + i);
    ushort4 o;
    o.x = f2bf(v.x); o.y = f2bf(v.y); o.z = f2bf(v.z); o.w = f2bf(v.w);
    *(ushort4*)(out + i) = o;
  }
}

// ---------------- GEMM: C[M,N] = A[M,K] * B[N,K]^T  (both K-major, bf16 in, f32 acc)
// m97 structure: 128x128 tile, BK=64, 4 waves (2x2), global_load_lds width=16.
template<int WRITE_BF16>
__global__ __launch_bounds__(256) void gemm_bt(const bf16* __restrict__ A,
                                               const bf16* __restrict__ B,
                                               void* __restrict__ Cout,
                                               int M, int N, int K) {
  __shared__ bf16 As[128 * 64];
  __shared__ bf16 Bs[128 * 64];
  const int tid  = threadIdx.x;
  const int lane = tid & 63;
  const int l15  = lane & 15, l4 = lane >> 4;
  const int wave = tid >> 6;
  const int wr = (wave >> 1) * 64;   // wave row offset in tile
  const int wc = (wave & 1) * 64;    // wave col offset in tile
  const int bm = blockIdx.y * 128, bn = blockIdx.x * 128;
  const int srow = tid >> 3;           // staging row 0..31 (per 32-row chunk)
  const int scol = (tid & 7) * 8;      // staging col (elements)

  const bf16* Ag = A + (size_t)(bm + srow) * K + scol;
  const bf16* Bg = B + (size_t)(bn + srow) * K + scol;
  bf16* Asw = As + tid * 8;            // linear LDS dest (lane-ordered, matches
  bf16* Bsw = Bs + tid * 8;            // wave-uniform-base + lane*16 DMA rule)

  f32x4 acc[4][4] = {};

  for (int k0 = 0; k0 < K; k0 += 64) {
#pragma unroll
    for (int i = 0; i < 4; ++i) {
      gload_lds16(Ag + (size_t)i * 32 * K + k0, Asw + i * 2048);
      gload_lds16(Bg + (size_t)i * 32 * K + k0, Bsw + i * 2048);
    }
    __syncthreads();
#pragma unroll
    for (int kk = 0; kk < 64; kk += 32) {
      bf16x8 af[4], bfr[4];
#pragma unroll
      for (int m = 0; m < 4; ++m)
        af[m] = *(const bf16x8*)(As + (wr + m * 16 + l15) * 64 + kk + l4 * 8);
#pragma unroll
      for (int n = 0; n < 4; ++n)
        bfr[n] = *(const bf16x8*)(Bs + (wc + n * 16 + l15) * 64 + kk + l4 * 8);
#pragma unroll
      for (int m = 0; m < 4; ++m)
#pragma unroll
        for (int n = 0; n < 4; ++n)
          acc[m][n] = __builtin_amdgcn_mfma_f32_16x16x32_bf16(af[m], bfr[n], acc[m][n], 0, 0, 0);
    }
    __syncthreads();
  }

  // C/D layout: col = lane&15, row = (lane>>4)*4 + j   [verified m89/m91]
  const int crow = bm + wr + l4 * 4;
  const int ccol = bn + wc + l15;
#pragma unroll
  for (int m = 0; m < 4; ++m)
#pragma unroll
    for (int n = 0; n < 4; ++n)
#pragma unroll
      for (int j = 0; j < 4; ++j) {
        size_t off = (size_t)(crow + m * 16 + j) * N + (ccol + n * 16);
        if (WRITE_BF16) ((bf16*)Cout)[off] = __float2bfloat16(acc[m][n][j]);
        else            ((float*)Cout)[off] = acc[m][n][j];
      }
}

// ---------------- fused RMSNorm (per 128-dim head) + RoPE, fp32 in -> bf16 out ----
// one wave per (t, head) row; lane holds (d, d+64) which is exactly the RoPE pair.
__global__ __launch_bounds__(256) void rmsrope_kernel(const float* __restrict__ X,
                                                      const float* __restrict__ cosb,
                                                      const float* __restrict__ sinb,
                                                      const float* __restrict__ g,
                                                      bf16* __restrict__ out, int heads) {
  const int wid  = blockIdx.x * 4 + (threadIdx.x >> 6);  // row index = t*heads + h
  const int lane = threadIdx.x & 63;
  const int t    = wid / heads;
  const size_t base = (size_t)wid * HD;
  float x1 = X[base + lane], x2 = X[base + lane + 64];
  float ss = x1 * x1 + x2 * x2;
#pragma unroll
  for (int off = 32; off >= 1; off >>= 1) ss += __shfl_xor(ss, off, 64);
  float scale = rsqrtf(ss * (1.0f / HD) + 1e-6f);
  float c = cosb[t * 64 + lane], s = sinb[t * 64 + lane];
  float xn1 = x1 * scale * g[lane];
  float xn2 = x2 * scale * g[lane + 64];
  out[base + lane]      = __float2bfloat16(xn1 * c - xn2 * s);
  out[base + lane + 64] = __float2bfloat16(xn2 * c + xn1 * s);
}

// ---------------- causal GQA flash attention ----------------
// grid (T/64, NH); block 256 = 4 waves; wave w owns q-rows [q0+16w, q0+16w+16).
// Heavy q-tiles (many K/V tiles) mapped to LOW blockIdx.x so they dispatch first.
// K in padded LDS [64][136] (2-way conflicts), V transposed to Vt[128][72],
// P via per-wave padded LDS [16][72] for C-layout -> A-layout transpose.
__global__ __launch_bounds__(256) void attn_kernel(const bf16* __restrict__ Q,
                                                   const bf16* __restrict__ Kg,
                                                   const bf16* __restrict__ Vg,
                                                   bf16* __restrict__ O) {
  __shared__ bf16 Ks[64][136];
  __shared__ bf16 Vt[128][72];
  __shared__ bf16 Ps[4][16][72];
  const int tid = threadIdx.x, lane = tid & 63, w = tid >> 6;
  const int l15 = lane & 15, l4 = lane >> 4;
  const int h = blockIdx.y;
  const int g = h >> 2;                 // GQA group (R = 4)
  const int qblk = gridDim.x - 1 - blockIdx.x;  // heavy tiles first
  const int q0 = qblk * 64;
  const int qrow = q0 + w * 16;

  // Q fragments (A operand): lane holds Q[qrow + (lane&15)][(lane>>4)*8 + ks*32 .. +8)
  const bf16* qp = Q + (size_t)(qrow + l15) * (NH * HD) + h * HD + l4 * 8;
  bf16x8 qf[4];
#pragma unroll
  for (int ks = 0; ks < 4; ++ks) qf[ks] = *(const bf16x8*)(qp + ks * 32);

  f32x4 o_acc[8] = {};
  float m_run[4], l_run[4];
#pragma unroll
  for (int j = 0; j < 4; ++j) { m_run[j] = -3e38f; l_run[j] = 0.f; }
  const float sc = 0.08838834764831845f;  // 1/sqrt(128)

  const int s_row = tid >> 4;          // 0..15 (staging)
  const int s_col = (tid & 15) * 8;    // 0..120
  const int nt = qblk + 1;             // causal: tiles s0 = 0 .. q0

  for (int it = 0; it < nt; ++it) {
    const int s0 = it * 64;
    // stage K (padded) + V (transposed, rotation-swizzled writes)
#pragma unroll
    for (int i = 0; i < 4; ++i) {
      const int r = i * 16 + s_row;
      bf16x8 kv = *(const bf16x8*)(Kg + (size_t)(s0 + r) * (NKV * HD) + g * HD + s_col);
      *(bf16x8*)(&Ks[r][s_col]) = kv;
      bf16x8 vv = *(const bf16x8*)(Vg + (size_t)(s0 + r) * (NKV * HD) + g * HD + s_col);
#pragma unroll
      for (int j = 0; j < 8; ++j) {
        const int jj = (j + s_row) & 7;       // rotate to break write bank conflicts
        Vt[s_col + jj][r] = ((const bf16*)&vv)[jj];
      }
    }
    __syncthreads();

    // S = Q K^T (16x64 per wave)
    f32x4 sf[4] = {};
#pragma unroll
    for (int nf = 0; nf < 4; ++nf)
#pragma unroll
      for (int ks = 0; ks < 4; ++ks) {
        bf16x8 kf = *(const bf16x8*)(&Ks[nf * 16 + l15][ks * 32 + l4 * 8]);
        sf[nf] = __builtin_amdgcn_mfma_f32_16x16x32_bf16(qf[ks], kf, sf[nf], 0, 0, 0);
      }

    // scale + causal mask (only the diagonal tile actually masks)
    const int colb = s0 + l15;
    const int rowb = qrow + l4 * 4;
#pragma unroll
    for (int nf = 0; nf < 4; ++nf)
#pragma unroll
      for (int j = 0; j < 4; ++j) {
        float v = sf[nf][j] * sc;
        sf[nf][j] = (colb + nf * 16 > rowb + j) ? -1e30f : v;
      }

    // online softmax per row (16 lanes per row: shfl_xor 8..1)
    float resc[4];
#pragma unroll
    for (int j = 0; j < 4; ++j) {
      float mx = fmaxf(fmaxf(sf[0][j], sf[1][j]), fmaxf(sf[2][j], sf[3][j]));
#pragma unroll
      for (int off = 8; off >= 1; off >>= 1) mx = fmaxf(mx, __shfl_xor(mx, off, 64));
      float mnew = fmaxf(m_run[j], mx);
      resc[j] = __expf(m_run[j] - mnew);
      m_run[j] = mnew;
      float ssum = 0.f;
#pragma unroll
      for (int nf = 0; nf < 4; ++nf) {
        float p = __expf(sf[nf][j] - mnew);
        sf[nf][j] = p;
        ssum += p;
      }
#pragma unroll
      for (int off = 8; off >= 1; off >>= 1) ssum += __shfl_xor(ssum, off, 64);
      l_run[j] = l_run[j] * resc[j] + ssum;
    }

    // rescale O, spill P (C-layout) to LDS as bf16
#pragma unroll
    for (int nf = 0; nf < 8; ++nf)
#pragma unroll
      for (int j = 0; j < 4; ++j) o_acc[nf][j] *= resc[j];
#pragma unroll
    for (int nf = 0; nf < 4; ++nf)
#pragma unroll
      for (int j = 0; j < 4; ++j)
        Ps[w][l4 * 4 + j][nf * 16 + l15] = __float2bfloat16(sf[nf][j]);

    // O += P V   (P re-read in A-layout; wave-local, compiler orders lgkmcnt)
#pragma unroll
    for (int ks = 0; ks < 2; ++ks) {
      bf16x8 pa = *(const bf16x8*)(&Ps[w][l15][ks * 32 + l4 * 8]);
#pragma unroll
      for (int nf = 0; nf < 8; ++nf) {
        bf16x8 vb = *(const bf16x8*)(&Vt[nf * 16 + l15][ks * 32 + l4 * 8]);
        o_acc[nf] = __builtin_amdgcn_mfma_f32_16x16x32_bf16(pa, vb, o_acc[nf], 0, 0, 0);
      }
    }
    __syncthreads();
  }

  // normalize + store (bf16, feeds O-projection GEMM)
#pragma unroll
  for (int nf = 0; nf < 8; ++nf)
#pragma unroll
    for (int j = 0; j < 4; ++j) {
      float v = o_acc[nf][j] / l_run[j];
      O[(size_t)(qrow + l4 * 4 + j) * (NH * HD) + h * HD + nf * 16 + l15] = __float2bfloat16(v);
    }
}

// ---------------- host ----------------
extern "C" void kernel_launch(void* const* d_in, const int* in_sizes, int n_in,
                              void* d_out, int out_size, void* d_ws, size_t ws_size,
                              hipStream_t stream) {
  (void)in_sizes; (void)n_in; (void)out_size; (void)ws_size;
  const float* x    = (const float*)d_in[0];
  const float* cosb = (const float*)d_in[1];
  const float* sinb = (const float*)d_in[2];
  const float* Wq   = (const float*)d_in[3];
  const float* Wk   = (const float*)d_in[4];
  const float* Wv   = (const float*)d_in[5];
  const float* Wo   = (const float*)d_in[6];
  const float* gq   = (const float*)d_in[7];
  const float* gk   = (const float*)d_in[8];

  char* ws = (char*)d_ws;
  size_t off = 0;
  auto alloc = [&](size_t bytes) { void* p = ws + off; off += (bytes + 255) & ~(size_t)255; return p; };
  bf16* xb   = (bf16*)alloc((size_t)T_SEQ * DIM * 2);
  bf16* Wqb  = (bf16*)alloc((size_t)NH * HD * DIM * 2);
  bf16* Wkb  = (bf16*)alloc((size_t)NKV * HD * DIM * 2);
  bf16* Wvb  = (bf16*)alloc((size_t)NKV * HD * DIM * 2);
  bf16* Wob  = (bf16*)alloc((size_t)DIM * NH * HD * 2);
  bf16* qb   = (bf16*)alloc((size_t)T_SEQ * NH * HD * 2);
  bf16* kb   = (bf16*)alloc((size_t)T_SEQ * NKV * HD * 2);
  bf16* vb   = (bf16*)alloc((size_t)T_SEQ * NKV * HD * 2);
  bf16* ao   = (bf16*)alloc((size_t)T_SEQ * NH * HD * 2);
  float* scr = (float*)alloc((size_t)T_SEQ * NH * HD * 4);  // reused: q_f32 then k_f32

  // converts
  cvt_kernel<<<2048, 256, 0, stream>>>(x,  (unsigned short*)xb,  T_SEQ * DIM);
  cvt_kernel<<<2048, 256, 0, stream>>>(Wq, (unsigned short*)Wqb, NH * HD * DIM);
  cvt_kernel<<<2048, 256, 0, stream>>>(Wk, (unsigned short*)Wkb, NKV * HD * DIM);
  cvt_kernel<<<2048, 256, 0, stream>>>(Wv, (unsigned short*)Wvb, NKV * HD * DIM);
  cvt_kernel<<<2048, 256, 0, stream>>>(Wo, (unsigned short*)Wob, DIM * NH * HD);

  // Q projection -> rmsnorm+rope
  gemm_bt<0><<<dim3(NH * HD / 128, T_SEQ / 128), 256, 0, stream>>>(xb, Wqb, scr, T_SEQ, NH * HD, DIM);
  rmsrope_kernel<<<T_SEQ * NH / 4, 256, 0, stream>>>(scr, cosb, sinb, gq, qb, NH);
  // K projection -> rmsnorm+rope
  gemm_bt<0><<<dim3(NKV * HD / 128, T_SEQ / 128), 256, 0, stream>>>(xb, Wkb, scr, T_SEQ, NKV * HD, DIM);
  rmsrope_kernel<<<T_SEQ * NKV / 4, 256, 0, stream>>>(scr, cosb, sinb, gk, kb, NKV);
  // V projection (bf16 epilogue, no norm)
  gemm_bt<1><<<dim3(NKV * HD / 128, T_SEQ / 128), 256, 0, stream>>>(xb, Wvb, vb, T_SEQ, NKV * HD, DIM);

  // attention
  attn_kernel<<<dim3(T_SEQ / 64, NH), 256, 0, stream>>>(qb, kb, vb, ao);

  // output projection -> fp32 d_out
  gemm_bt<0><<<dim3(DIM / 128, T_SEQ / 128), 256, 0, stream>>>(ao, Wob, (float*)d_out, T_SEQ, DIM, NH * HD);
}

// Round 6
// 659.448 us; speedup vs baseline: 1.5391x; 1.5391x over previous
//
#include <hip/hip_runtime.h>
#include <hip/hip_bf16.h>
#include <stdint.h>
#include <stddef.h>

#define T_SEQ 2048
#define DIM   4096
#define NH    32
#define NKV   8
#define HD    128
#define QKV_N 6144   // 4096 (Q) + 1024 (K) + 1024 (V)

using bf16 = __hip_bfloat16;
typedef __attribute__((ext_vector_type(8))) short bf16x8;
typedef __attribute__((ext_vector_type(4))) float f32x4;

__device__ __forceinline__ void gload_lds16(const void* g, void* l) {
  __builtin_amdgcn_global_load_lds(
      (const __attribute__((address_space(1))) unsigned int*)g,
      (__attribute__((address_space(3))) unsigned int*)l, 16, 0, 0);
}

__device__ __forceinline__ unsigned short f2bf(float x) {
  bf16 h = __float2bfloat16(x);
  return *reinterpret_cast<unsigned short*>(&h);
}

// ---------------- fp32 -> bf16 convert (vectorized, grid-stride) ----------------
__global__ __launch_bounds__(256) void cvt_kernel(const float* __restrict__ in,
                                                  unsigned short* __restrict__ out, int n) {
  const int idx = blockIdx.x * blockDim.x + threadIdx.x;
  const int stride = gridDim.x * blockDim.x;
  for (int i = idx * 4; i < n; i += stride * 4) {
    float4 v = *(const float4*)(in + i);
    ushort4 o;
    o.x = f2bf(v.x); o.y = f2bf(v.y); o.z = f2bf(v.z); o.w = f2bf(v.w);
    *(ushort4*)(out + i) = o;
  }
}

// ---------------- GEMM: C[M,N] = A[M,K] * B[N,K]^T  (both K-major, bf16 in, f32 acc)
// m97 structure: 128x128 tile, BK=64, 4 waves (2x2), global_load_lds width=16.
template<int WRITE_BF16>
__global__ __launch_bounds__(256) void gemm_bt(const bf16* __restrict__ A,
                                               const bf16* __restrict__ B,
                                               void* __restrict__ Cout,
                                               int M, int N, int K) {
  __shared__ bf16 As[128 * 64];
  __shared__ bf16 Bs[128 * 64];
  const int tid  = threadIdx.x;
  const int lane = tid & 63;
  const int l15  = lane & 15, l4 = lane >> 4;
  const int wave = tid >> 6;
  const int wr = (wave >> 1) * 64;
  const int wc = (wave & 1) * 64;
  const int bm = blockIdx.y * 128, bn = blockIdx.x * 128;
  const int srow = tid >> 3;
  const int scol = (tid & 7) * 8;

  const bf16* Ag = A + (size_t)(bm + srow) * K + scol;
  const bf16* Bg = B + (size_t)(bn + srow) * K + scol;
  bf16* Asw = As + tid * 8;   // linear LDS dest (wave-uniform base + lane*16)
  bf16* Bsw = Bs + tid * 8;

  f32x4 acc[4][4] = {};

  for (int k0 = 0; k0 < K; k0 += 64) {
#pragma unroll
    for (int i = 0; i < 4; ++i) {
      gload_lds16(Ag + (size_t)i * 32 * K + k0, Asw + i * 2048);
      gload_lds16(Bg + (size_t)i * 32 * K + k0, Bsw + i * 2048);
    }
    __syncthreads();
#pragma unroll
    for (int kk = 0; kk < 64; kk += 32) {
      bf16x8 af[4], bfr[4];
#pragma unroll
      for (int m = 0; m < 4; ++m)
        af[m] = *(const bf16x8*)(As + (wr + m * 16 + l15) * 64 + kk + l4 * 8);
#pragma unroll
      for (int n = 0; n < 4; ++n)
        bfr[n] = *(const bf16x8*)(Bs + (wc + n * 16 + l15) * 64 + kk + l4 * 8);
#pragma unroll
      for (int m = 0; m < 4; ++m)
#pragma unroll
        for (int n = 0; n < 4; ++n)
          acc[m][n] = __builtin_amdgcn_mfma_f32_16x16x32_bf16(af[m], bfr[n], acc[m][n], 0, 0, 0);
    }
    __syncthreads();
  }

  // C/D layout: col = lane&15, row = (lane>>4)*4 + j   [verified m89/m91]
  const int crow = bm + wr + l4 * 4;
  const int ccol = bn + wc + l15;
#pragma unroll
  for (int m = 0; m < 4; ++m)
#pragma unroll
    for (int n = 0; n < 4; ++n)
#pragma unroll
      for (int j = 0; j < 4; ++j) {
        size_t off = (size_t)(crow + m * 16 + j) * N + (ccol + n * 16);
        if (WRITE_BF16) ((bf16*)Cout)[off] = __float2bfloat16(acc[m][n][j]);
        else            ((float*)Cout)[off] = acc[m][n][j];
      }
}

// ---------------- fused RMSNorm (per 128-dim head) + RoPE, bf16 in -> bf16 out ----
// one wave per (t, head) row; lane holds (d, d+64) which is exactly the RoPE pair.
__global__ __launch_bounds__(256) void rmsrope_kernel(const bf16* __restrict__ X,
                                                      const float* __restrict__ cosb,
                                                      const float* __restrict__ sinb,
                                                      const float* __restrict__ g,
                                                      bf16* __restrict__ out,
                                                      int heads, int instride, int inoff) {
  const int wid  = blockIdx.x * 4 + (threadIdx.x >> 6);  // (t, h) index
  const int lane = threadIdx.x & 63;
  const int t    = wid / heads;
  const int h    = wid - t * heads;
  const bf16* xin = X + (size_t)t * instride + inoff + h * HD;
  float x1 = __bfloat162float(xin[lane]);
  float x2 = __bfloat162float(xin[lane + 64]);
  float ss = x1 * x1 + x2 * x2;
#pragma unroll
  for (int off = 32; off >= 1; off >>= 1) ss += __shfl_xor(ss, off, 64);
  float scale = rsqrtf(ss * (1.0f / HD) + 1e-6f);
  float c = cosb[t * 64 + lane], s = sinb[t * 64 + lane];
  float xn1 = x1 * scale * g[lane];
  float xn2 = x2 * scale * g[lane + 64];
  bf16* op = out + (size_t)wid * HD;
  op[lane]      = __float2bfloat16(xn1 * c - xn2 * s);
  op[lane + 64] = __float2bfloat16(xn2 * c + xn1 * s);
}

// ---------------- causal GQA flash attention (group-folded) ----------------
// grid 512 blocks: bid -> g = bid&7, qblk = 63 - bid>>3 (heavy tiles dispatch first).
// block = 512 thr = 8 waves; wave w: head g*4 + (w>>1), q-rows qblk*32 + (w&1)*16 .. +16.
// K/V staged ONCE per group (shared by 4 heads). V transpose is conflict-free:
// each write instr has uniform d, lane = kv-row -> banks 0..31, 2-way same-dword.
__global__ __launch_bounds__(512) void attn_kernel(const bf16* __restrict__ Q,
                                                   const bf16* __restrict__ Kg,
                                                   const bf16* __restrict__ Vg,
                                                   bf16* __restrict__ O) {
  __shared__ bf16 Ks[64][136];   // row-major K tile, padded (aligned 16B rows)
  __shared__ bf16 Vt[128][72];   // transposed V tile [d][s]
  __shared__ bf16 Ps[8][16][72]; // per-wave P spill (C-layout -> A-layout)
  const int tid = threadIdx.x, lane = tid & 63, w = tid >> 6;
  const int l15 = lane & 15, l4 = lane >> 4;
  const int g = blockIdx.x & 7;
  const int qblk = 63 - (int)(blockIdx.x >> 3);
  const int h = g * 4 + (w >> 1);
  const int qrow = qblk * 32 + (w & 1) * 16;
  const int nt = (qblk >> 1) + 1;   // causal KV-tile count

  // Q fragments (A operand): lane holds Q[qrow + l15][l4*8 + ks*32 .. +8)
  const bf16* qp = Q + (size_t)(qrow + l15) * (NH * HD) + h * HD + l4 * 8;
  bf16x8 qf[4];
#pragma unroll
  for (int ks = 0; ks < 4; ++ks) qf[ks] = *(const bf16x8*)(qp + ks * 32);

  f32x4 o_acc[8] = {};
  float m_run[4], l_run[4];
#pragma unroll
  for (int j = 0; j < 4; ++j) { m_run[j] = -3e38f; l_run[j] = 0.f; }
  const float sc = 0.08838834764831845f;  // 1/sqrt(128)

  const int kr = tid >> 4;           // K staging row 0..31
  const int kc = (tid & 15) * 8;     // K staging col

  for (int it = 0; it < nt; ++it) {
    const int s0 = it * 64;
    // K stage: coalesced (16 lanes x 8 elems = 256B per row)
#pragma unroll
    for (int i = 0; i < 2; ++i) {
      const int r = kr + i * 32;
      bf16x8 kv = *(const bf16x8*)(Kg + (size_t)(s0 + r) * (NKV * HD) + g * HD + kc);
      *(bf16x8*)(&Ks[r][kc]) = kv;
    }
    // V stage: lane = kv-row, per-wave d-block; transpose writes conflict-free
#pragma unroll
    for (int i = 0; i < 2; ++i) {
      const int dblk = w * 2 + i;    // 0..15
      bf16x8 vv = *(const bf16x8*)(Vg + (size_t)(s0 + lane) * QKV_N + g * HD + dblk * 8);
#pragma unroll
      for (int jj = 0; jj < 8; ++jj)
        *reinterpret_cast<short*>(&Vt[dblk * 8 + jj][lane]) = vv[jj];
    }
    __syncthreads();

    // S = Q K^T (16x64 per wave)
    f32x4 sf[4] = {};
#pragma unroll
    for (int nf = 0; nf < 4; ++nf)
#pragma unroll
      for (int ks = 0; ks < 4; ++ks) {
        bf16x8 kf = *(const bf16x8*)(&Ks[nf * 16 + l15][ks * 32 + l4 * 8]);
        sf[nf] = __builtin_amdgcn_mfma_f32_16x16x32_bf16(qf[ks], kf, sf[nf], 0, 0, 0);
      }

    // scale + causal mask
    const int colb = s0 + l15;
    const int rowb = qrow + l4 * 4;
#pragma unroll
    for (int nf = 0; nf < 4; ++nf)
#pragma unroll
      for (int j = 0; j < 4; ++j) {
        float v = sf[nf][j] * sc;
        sf[nf][j] = (colb + nf * 16 > rowb + j) ? -1e30f : v;
      }

    // online softmax per row (16 lanes per row)
    float resc[4];
#pragma unroll
    for (int j = 0; j < 4; ++j) {
      float mx = fmaxf(fmaxf(sf[0][j], sf[1][j]), fmaxf(sf[2][j], sf[3][j]));
#pragma unroll
      for (int off = 8; off >= 1; off >>= 1) mx = fmaxf(mx, __shfl_xor(mx, off, 64));
      float mnew = fmaxf(m_run[j], mx);
      resc[j] = __expf(m_run[j] - mnew);
      m_run[j] = mnew;
      float ssum = 0.f;
#pragma unroll
      for (int nf = 0; nf < 4; ++nf) {
        float p = __expf(sf[nf][j] - mnew);
        sf[nf][j] = p;
        ssum += p;
      }
#pragma unroll
      for (int off = 8; off >= 1; off >>= 1) ssum += __shfl_xor(ssum, off, 64);
      l_run[j] = l_run[j] * resc[j] + ssum;
    }

    // rescale O, spill P (C-layout) to LDS as bf16
#pragma unroll
    for (int nf = 0; nf < 8; ++nf)
#pragma unroll
      for (int j = 0; j < 4; ++j) o_acc[nf][j] *= resc[j];
#pragma unroll
    for (int nf = 0; nf < 4; ++nf)
#pragma unroll
      for (int j = 0; j < 4; ++j)
        Ps[w][l4 * 4 + j][nf * 16 + l15] = __float2bfloat16(sf[nf][j]);

    // O += P V   (P re-read in A-layout; wave-local)
#pragma unroll
    for (int ks = 0; ks < 2; ++ks) {
      bf16x8 pa = *(const bf16x8*)(&Ps[w][l15][ks * 32 + l4 * 8]);
#pragma unroll
      for (int nf = 0; nf < 8; ++nf) {
        bf16x8 vb = *(const bf16x8*)(&Vt[nf * 16 + l15][ks * 32 + l4 * 8]);
        o_acc[nf] = __builtin_amdgcn_mfma_f32_16x16x32_bf16(pa, vb, o_acc[nf], 0, 0, 0);
      }
    }
    __syncthreads();
  }

  // normalize + store (bf16, feeds O-projection GEMM)
#pragma unroll
  for (int nf = 0; nf < 8; ++nf)
#pragma unroll
    for (int j = 0; j < 4; ++j) {
      float v = o_acc[nf][j] / l_run[j];
      O[(size_t)(qrow + l4 * 4 + j) * (NH * HD) + h * HD + nf * 16 + l15] = __float2bfloat16(v);
    }
}

// ---------------- host ----------------
extern "C" void kernel_launch(void* const* d_in, const int* in_sizes, int n_in,
                              void* d_out, int out_size, void* d_ws, size_t ws_size,
                              hipStream_t stream) {
  (void)in_sizes; (void)n_in; (void)out_size; (void)ws_size;
  const float* x    = (const float*)d_in[0];
  const float* cosb = (const float*)d_in[1];
  const float* sinb = (const float*)d_in[2];
  const float* Wq   = (const float*)d_in[3];
  const float* Wk   = (const float*)d_in[4];
  const float* Wv   = (const float*)d_in[5];
  const float* Wo   = (const float*)d_in[6];
  const float* gq   = (const float*)d_in[7];
  const float* gk   = (const float*)d_in[8];

  char* ws = (char*)d_ws;
  size_t off = 0;
  auto alloc = [&](size_t bytes) { void* p = ws + off; off += (bytes + 255) & ~(size_t)255; return p; };
  bf16* xb   = (bf16*)alloc((size_t)T_SEQ * DIM * 2);
  // Wq/Wk/Wv MUST be contiguous: fused B matrix [6144][4096]
  bf16* Wqb  = (bf16*)alloc((size_t)NH * HD * DIM * 2);
  bf16* Wkb  = (bf16*)alloc((size_t)NKV * HD * DIM * 2);
  bf16* Wvb  = (bf16*)alloc((size_t)NKV * HD * DIM * 2);
  bf16* Wob  = (bf16*)alloc((size_t)DIM * NH * HD * 2);
  bf16* qkv  = (bf16*)alloc((size_t)T_SEQ * QKV_N * 2);   // [T][6144]
  bf16* qb   = (bf16*)alloc((size_t)T_SEQ * NH * HD * 2);  // post-rope Q [T][4096]
  bf16* kb   = (bf16*)alloc((size_t)T_SEQ * NKV * HD * 2); // post-rope K [T][1024]
  bf16* ao   = (bf16*)alloc((size_t)T_SEQ * NH * HD * 2);  // attn out [T][4096]

  // converts
  cvt_kernel<<<2048, 256, 0, stream>>>(x,  (unsigned short*)xb,  T_SEQ * DIM);
  cvt_kernel<<<2048, 256, 0, stream>>>(Wq, (unsigned short*)Wqb, NH * HD * DIM);
  cvt_kernel<<<2048, 256, 0, stream>>>(Wk, (unsigned short*)Wkb, NKV * HD * DIM);
  cvt_kernel<<<2048, 256, 0, stream>>>(Wv, (unsigned short*)Wvb, NKV * HD * DIM);
  cvt_kernel<<<2048, 256, 0, stream>>>(Wo, (unsigned short*)Wob, DIM * NH * HD);

  // fused QKV projection: C[2048][6144] = xb @ [Wq;Wk;Wv]^T
  gemm_bt<1><<<dim3(QKV_N / 128, T_SEQ / 128), 256, 0, stream>>>(xb, Wqb, qkv, T_SEQ, QKV_N, DIM);

  // RMSNorm + RoPE (bf16 in, strided into qkv)
  rmsrope_kernel<<<T_SEQ * NH  / 4, 256, 0, stream>>>(qkv, cosb, sinb, gq, qb, NH,  QKV_N, 0);
  rmsrope_kernel<<<T_SEQ * NKV / 4, 256, 0, stream>>>(qkv, cosb, sinb, gk, kb, NKV, QKV_N, DIM);

  // attention (V read directly from qkv at offset 5120, stride 6144)
  attn_kernel<<<512, 512, 0, stream>>>(qb, kb, qkv + DIM + NKV * HD, ao);

  // output projection -> fp32 d_out
  gemm_bt<0><<<dim3(DIM / 128, T_SEQ / 128), 256, 0, stream>>>(ao, Wob, (float*)d_out, T_SEQ, DIM, NH * HD);
}

// Round 8
// 657.230 us; speedup vs baseline: 1.5443x; 1.0034x over previous
//
#include <hip/hip_runtime.h>
#include <hip/hip_bf16.h>
#include <stdint.h>
#include <stddef.h>

#define T_SEQ 2048
#define DIM   4096
#define NH    32
#define NKV   8
#define HD    128
#define QKV_N 6144   // 4096 (Q) + 1024 (K) + 1024 (V)

using bf16 = __hip_bfloat16;
typedef __attribute__((ext_vector_type(8))) short bf16x8;
typedef __attribute__((ext_vector_type(4))) float f32x4;

__device__ __forceinline__ void gload_lds16(const void* g, void* l) {
  __builtin_amdgcn_global_load_lds(
      (const __attribute__((address_space(1))) unsigned int*)g,
      (__attribute__((address_space(3))) unsigned int*)l, 16, 0, 0);
}

__device__ __forceinline__ unsigned short f2bf(float x) {
  bf16 h = __float2bfloat16(x);
  return *reinterpret_cast<unsigned short*>(&h);
}

// ---------------- fused fp32 -> bf16 convert: 5 regions in ONE dispatch ----------
// (saves 4 launch ramp/tail overheads; all sizes are multiples of 4)
__global__ __launch_bounds__(256) void cvt5_kernel(
    const float* __restrict__ i0, const float* __restrict__ i1,
    const float* __restrict__ i2, const float* __restrict__ i3,
    const float* __restrict__ i4,
    unsigned short* __restrict__ o0, unsigned short* __restrict__ o1,
    unsigned short* __restrict__ o2, unsigned short* __restrict__ o3,
    unsigned short* __restrict__ o4,
    int n0, int n1, int n2, int n3, int n4) {
  const int c1 = n0, c2 = c1 + n1, c3 = c2 + n2, c4 = c3 + n3, c5 = c4 + n4;
  const int idx = blockIdx.x * blockDim.x + threadIdx.x;
  const int stride = gridDim.x * blockDim.x;
  for (int i = idx * 4; i < c5; i += stride * 4) {
    const float* in; unsigned short* out; int off;
    if      (i < c1) { in = i0; out = o0; off = i; }
    else if (i < c2) { in = i1; out = o1; off = i - c1; }
    else if (i < c3) { in = i2; out = o2; off = i - c2; }
    else if (i < c4) { in = i3; out = o3; off = i - c3; }
    else             { in = i4; out = o4; off = i - c4; }
    float4 v = *(const float4*)(in + off);
    ushort4 o;
    o.x = f2bf(v.x); o.y = f2bf(v.y); o.z = f2bf(v.z); o.w = f2bf(v.w);
    *(ushort4*)(out + off) = o;
  }
}

// ---------------- GEMM: C[M,N] = A[M,K] * B[N,K]^T  (both K-major, bf16 in, f32 acc)
// m97 structure: 128x128 tile, BK=64, 4 waves (2x2), global_load_lds width=16.
// 1D grid + T1 XCD-chunked swizzle: XCD k gets a contiguous row-major chunk of
// tiles -> each A row-panel is fetched by exactly one XCD (was: all 8).
// REQUIRES gridDim.x % 8 == 0 (768 and 512 here).
template<int WRITE_BF16>
__global__ __launch_bounds__(256) void gemm_bt(const bf16* __restrict__ A,
                                               const bf16* __restrict__ B,
                                               void* __restrict__ Cout,
                                               int M, int N, int K, int gx) {
  __shared__ bf16 As[128 * 64];
  __shared__ bf16 Bs[128 * 64];
  const int nwg = gridDim.x;
  const int q   = nwg >> 3;                       // chunk per XCD
  const int swz = (blockIdx.x & 7) * q + (blockIdx.x >> 3);
  const int bx  = swz % gx, by = swz / gx;
  const int tid  = threadIdx.x;
  const int lane = tid & 63;
  const int l15  = lane & 15, l4 = lane >> 4;
  const int wave = tid >> 6;
  const int wr = (wave >> 1) * 64;
  const int wc = (wave & 1) * 64;
  const int bm = by * 128, bn = bx * 128;
  const int srow = tid >> 3;
  const int scol = (tid & 7) * 8;

  const bf16* Ag = A + (size_t)(bm + srow) * K + scol;
  const bf16* Bg = B + (size_t)(bn + srow) * K + scol;
  bf16* Asw = As + tid * 8;   // linear LDS dest (wave-uniform base + lane*16)
  bf16* Bsw = Bs + tid * 8;

  f32x4 acc[4][4] = {};

  for (int k0 = 0; k0 < K; k0 += 64) {
#pragma unroll
    for (int i = 0; i < 4; ++i) {
      gload_lds16(Ag + (size_t)i * 32 * K + k0, Asw + i * 2048);
      gload_lds16(Bg + (size_t)i * 32 * K + k0, Bsw + i * 2048);
    }
    __syncthreads();
#pragma unroll
    for (int kk = 0; kk < 64; kk += 32) {
      bf16x8 af[4], bfr[4];
#pragma unroll
      for (int m = 0; m < 4; ++m)
        af[m] = *(const bf16x8*)(As + (wr + m * 16 + l15) * 64 + kk + l4 * 8);
#pragma unroll
      for (int n = 0; n < 4; ++n)
        bfr[n] = *(const bf16x8*)(Bs + (wc + n * 16 + l15) * 64 + kk + l4 * 8);
#pragma unroll
      for (int m = 0; m < 4; ++m)
#pragma unroll
        for (int n = 0; n < 4; ++n)
          acc[m][n] = __builtin_amdgcn_mfma_f32_16x16x32_bf16(af[m], bfr[n], acc[m][n], 0, 0, 0);
    }
    __syncthreads();
  }

  // C/D layout: col = lane&15, row = (lane>>4)*4 + j   [verified m89/m91]
  const int crow = bm + wr + l4 * 4;
  const int ccol = bn + wc + l15;
#pragma unroll
  for (int m = 0; m < 4; ++m)
#pragma unroll
    for (int n = 0; n < 4; ++n)
#pragma unroll
      for (int j = 0; j < 4; ++j) {
        size_t off = (size_t)(crow + m * 16 + j) * N + (ccol + n * 16);
        if (WRITE_BF16) ((bf16*)Cout)[off] = __float2bfloat16(acc[m][n][j]);
        else            ((float*)Cout)[off] = acc[m][n][j];
      }
}

// ---------------- fused RMSNorm (per 128-dim head) + RoPE, bf16 in -> bf16 out ----
// one wave per (t, head) row; lane holds (d, d+64) which is exactly the RoPE pair.
__global__ __launch_bounds__(256) void rmsrope_kernel(const bf16* __restrict__ X,
                                                      const float* __restrict__ cosb,
                                                      const float* __restrict__ sinb,
                                                      const float* __restrict__ g,
                                                      bf16* __restrict__ out,
                                                      int heads, int instride, int inoff) {
  const int wid  = blockIdx.x * 4 + (threadIdx.x >> 6);  // (t, h) index
  const int lane = threadIdx.x & 63;
  const int t    = wid / heads;
  const int h    = wid - t * heads;
  const bf16* xin = X + (size_t)t * instride + inoff + h * HD;
  float x1 = __bfloat162float(xin[lane]);
  float x2 = __bfloat162float(xin[lane + 64]);
  float ss = x1 * x1 + x2 * x2;
#pragma unroll
  for (int off = 32; off >= 1; off >>= 1) ss += __shfl_xor(ss, off, 64);
  float scale = rsqrtf(ss * (1.0f / HD) + 1e-6f);
  float c = cosb[t * 64 + lane], s = sinb[t * 64 + lane];
  float xn1 = x1 * scale * g[lane];
  float xn2 = x2 * scale * g[lane + 64];
  bf16* op = out + (size_t)wid * HD;
  op[lane]      = __float2bfloat16(xn1 * c - xn2 * s);
  op[lane + 64] = __float2bfloat16(xn2 * c + xn1 * s);
}

// ---------------- causal GQA flash attention (group-folded) ----------------
// grid 512 blocks: bid -> g = bid&7 (== XCD id: each group's K/V stays in ONE
// XCD's L2), qblk = 63 - bid>>3 (heavy tiles dispatch first).
// block = 512 thr = 8 waves; wave w: head g*4 + (w>>1), q-rows qblk*32 + (w&1)*16.
// K/V staged ONCE per group (shared by 4 heads). V transpose is conflict-free:
// each write instr has uniform d, lane = kv-row -> banks 0..31, 2-way same-dword.
__global__ __launch_bounds__(512) void attn_kernel(const bf16* __restrict__ Q,
                                                   const bf16* __restrict__ Kg,
                                                   const bf16* __restrict__ Vg,
                                                   bf16* __restrict__ O) {
  __shared__ bf16 Ks[64][136];   // row-major K tile, padded (aligned 16B rows)
  __shared__ bf16 Vt[128][72];   // transposed V tile [d][s]
  __shared__ bf16 Ps[8][16][72]; // per-wave P spill (C-layout -> A-layout)
  const int tid = threadIdx.x, lane = tid & 63, w = tid >> 6;
  const int l15 = lane & 15, l4 = lane >> 4;
  const int g = blockIdx.x & 7;
  const int qblk = 63 - (int)(blockIdx.x >> 3);
  const int h = g * 4 + (w >> 1);
  const int qrow = qblk * 32 + (w & 1) * 16;
  const int nt = (qblk >> 1) + 1;   // causal KV-tile count

  // Q fragments (A operand): lane holds Q[qrow + l15][l4*8 + ks*32 .. +8)
  const bf16* qp = Q + (size_t)(qrow + l15) * (NH * HD) + h * HD + l4 * 8;
  bf16x8 qf[4];
#pragma unroll
  for (int ks = 0; ks < 4; ++ks) qf[ks] = *(const bf16x8*)(qp + ks * 32);

  f32x4 o_acc[8] = {};
  float m_run[4], l_run[4];
#pragma unroll
  for (int j = 0; j < 4; ++j) { m_run[j] = -3e38f; l_run[j] = 0.f; }
  const float sc = 0.08838834764831845f;  // 1/sqrt(128)

  const int kr = tid >> 4;           // K staging row 0..31
  const int kc = (tid & 15) * 8;     // K staging col

  for (int it = 0; it < nt; ++it) {
    const int s0 = it * 64;
    // K stage: coalesced (16 lanes x 8 elems = 256B per row)
#pragma unroll
    for (int i = 0; i < 2; ++i) {
      const int r = kr + i * 32;
      bf16x8 kv = *(const bf16x8*)(Kg + (size_t)(s0 + r) * (NKV * HD) + g * HD + kc);
      *(bf16x8*)(&Ks[r][kc]) = kv;
    }
    // V stage: lane = kv-row, per-wave d-block; transpose writes conflict-free
#pragma unroll
    for (int i = 0; i < 2; ++i) {
      const int dblk = w * 2 + i;    // 0..15
      bf16x8 vv = *(const bf16x8*)(Vg + (size_t)(s0 + lane) * QKV_N + g * HD + dblk * 8);
#pragma unroll
      for (int jj = 0; jj < 8; ++jj)
        *reinterpret_cast<short*>(&Vt[dblk * 8 + jj][lane]) = vv[jj];
    }
    __syncthreads();

    // S = Q K^T (16x64 per wave)
    f32x4 sf[4] = {};
#pragma unroll
    for (int nf = 0; nf < 4; ++nf)
#pragma unroll
      for (int ks = 0; ks < 4; ++ks) {
        bf16x8 kf = *(const bf16x8*)(&Ks[nf * 16 + l15][ks * 32 + l4 * 8]);
        sf[nf] = __builtin_amdgcn_mfma_f32_16x16x32_bf16(qf[ks], kf, sf[nf], 0, 0, 0);
      }

    // scale + causal mask
    const int colb = s0 + l15;
    const int rowb = qrow + l4 * 4;
#pragma unroll
    for (int nf = 0; nf < 4; ++nf)
#pragma unroll
      for (int j = 0; j < 4; ++j) {
        float v = sf[nf][j] * sc;
        sf[nf][j] = (colb + nf * 16 > rowb + j) ? -1e30f : v;
      }

    // online softmax per row (16 lanes per row)
    float resc[4];
#pragma unroll
    for (int j = 0; j < 4; ++j) {
      float mx = fmaxf(fmaxf(sf[0][j], sf[1][j]), fmaxf(sf[2][j], sf[3][j]));
#pragma unroll
      for (int off = 8; off >= 1; off >>= 1) mx = fmaxf(mx, __shfl_xor(mx, off, 64));
      float mnew = fmaxf(m_run[j], mx);
      resc[j] = __expf(m_run[j] - mnew);
      m_run[j] = mnew;
      float ssum = 0.f;
#pragma unroll
      for (int nf = 0; nf < 4; ++nf) {
        float p = __expf(sf[nf][j] - mnew);
        sf[nf][j] = p;
        ssum += p;
      }
#pragma unroll
      for (int off = 8; off >= 1; off >>= 1) ssum += __shfl_xor(ssum, off, 64);
      l_run[j] = l_run[j] * resc[j] + ssum;
    }

    // rescale O, spill P (C-layout) to LDS as bf16
#pragma unroll
    for (int nf = 0; nf < 8; ++nf)
#pragma unroll
      for (int j = 0; j < 4; ++j) o_acc[nf][j] *= resc[j];
#pragma unroll
    for (int nf = 0; nf < 4; ++nf)
#pragma unroll
      for (int j = 0; j < 4; ++j)
        Ps[w][l4 * 4 + j][nf * 16 + l15] = __float2bfloat16(sf[nf][j]);

    // O += P V   (P re-read in A-layout; wave-local)
#pragma unroll
    for (int ks = 0; ks < 2; ++ks) {
      bf16x8 pa = *(const bf16x8*)(&Ps[w][l15][ks * 32 + l4 * 8]);
#pragma unroll
      for (int nf = 0; nf < 8; ++nf) {
        bf16x8 vb = *(const bf16x8*)(&Vt[nf * 16 + l15][ks * 32 + l4 * 8]);
        o_acc[nf] = __builtin_amdgcn_mfma_f32_16x16x32_bf16(pa, vb, o_acc[nf], 0, 0, 0);
      }
    }
    __syncthreads();
  }

  // normalize + store (bf16, feeds O-projection GEMM)
#pragma unroll
  for (int nf = 0; nf < 8; ++nf)
#pragma unroll
    for (int j = 0; j < 4; ++j) {
      float v = o_acc[nf][j] / l_run[j];
      O[(size_t)(qrow + l4 * 4 + j) * (NH * HD) + h * HD + nf * 16 + l15] = __float2bfloat16(v);
    }
}

// ---------------- host ----------------
extern "C" void kernel_launch(void* const* d_in, const int* in_sizes, int n_in,
                              void* d_out, int out_size, void* d_ws, size_t ws_size,
                              hipStream_t stream) {
  (void)in_sizes; (void)n_in; (void)out_size; (void)ws_size;
  const float* x    = (const float*)d_in[0];
  const float* cosb = (const float*)d_in[1];
  const float* sinb = (const float*)d_in[2];
  const float* Wq   = (const float*)d_in[3];
  const float* Wk   = (const float*)d_in[4];
  const float* Wv   = (const float*)d_in[5];
  const float* Wo   = (const float*)d_in[6];
  const float* gq   = (const float*)d_in[7];
  const float* gk   = (const float*)d_in[8];

  char* ws = (char*)d_ws;
  size_t off = 0;
  auto alloc = [&](size_t bytes) { void* p = ws + off; off += (bytes + 255) & ~(size_t)255; return p; };
  bf16* xb   = (bf16*)alloc((size_t)T_SEQ * DIM * 2);
  // Wq/Wk/Wv MUST be contiguous: fused B matrix [6144][4096]
  bf16* Wqb  = (bf16*)alloc((size_t)NH * HD * DIM * 2);
  bf16* Wkb  = (bf16*)alloc((size_t)NKV * HD * DIM * 2);
  bf16* Wvb  = (bf16*)alloc((size_t)NKV * HD * DIM * 2);
  bf16* Wob  = (bf16*)alloc((size_t)DIM * NH * HD * 2);
  bf16* qkv  = (bf16*)alloc((size_t)T_SEQ * QKV_N * 2);   // [T][6144]
  bf16* qb   = (bf16*)alloc((size_t)T_SEQ * NH * HD * 2);  // post-rope Q [T][4096]
  bf16* kb   = (bf16*)alloc((size_t)T_SEQ * NKV * HD * 2); // post-rope K [T][1024]
  bf16* ao   = (bf16*)alloc((size_t)T_SEQ * NH * HD * 2);  // attn out [T][4096]

  // single fused convert (x + 4 weight matrices)
  cvt5_kernel<<<2048, 256, 0, stream>>>(
      x, Wq, Wk, Wv, Wo,
      (unsigned short*)xb, (unsigned short*)Wqb, (unsigned short*)Wkb,
      (unsigned short*)Wvb, (unsigned short*)Wob,
      T_SEQ * DIM, NH * HD * DIM, NKV * HD * DIM, NKV * HD * DIM, DIM * NH * HD);

  // fused QKV projection: C[2048][6144] = xb @ [Wq;Wk;Wv]^T   (768 WGs, %8==0)
  gemm_bt<1><<<(QKV_N / 128) * (T_SEQ / 128), 256, 0, stream>>>(
      xb, Wqb, qkv, T_SEQ, QKV_N, DIM, QKV_N / 128);

  // RMSNorm + RoPE (bf16 in, strided into qkv)
  rmsrope_kernel<<<T_SEQ * NH  / 4, 256, 0, stream>>>(qkv, cosb, sinb, gq, qb, NH,  QKV_N, 0);
  rmsrope_kernel<<<T_SEQ * NKV / 4, 256, 0, stream>>>(qkv, cosb, sinb, gk, kb, NKV, QKV_N, DIM);

  // attention (V read directly from qkv at offset 5120, stride 6144)
  attn_kernel<<<512, 512, 0, stream>>>(qb, kb, qkv + DIM + NKV * HD, ao);

  // output projection -> fp32 d_out   (512 WGs, %8==0)
  gemm_bt<0><<<(DIM / 128) * (T_SEQ / 128), 256, 0, stream>>>(
      ao, Wob, (float*)d_out, T_SEQ, DIM, NH * HD, DIM / 128);
}